// Round 5
// baseline (863.908 us; speedup 1.0000x reference)
//
#include <hip/hip_runtime.h>
#include <hip/hip_bf16.h>
#include <math.h>

#define NF 50000
#define NM 5000
#define EFF 800000
#define EMF 200000

typedef __attribute__((ext_vector_type(8))) short s8;
typedef __attribute__((ext_vector_type(4))) float f4;

__device__ __forceinline__ short f2b(float f) {
    __hip_bfloat16 h = __float2bfloat16(f);
    return *reinterpret_cast<short*>(&h);
}

// ---- Phase A: timestep embedding + FiLM (tiny) ----
__global__ void k_small(const float* __restrict__ tau,
                        const float* __restrict__ tcW1, const float* __restrict__ tcb1,
                        const float* __restrict__ tcW2, const float* __restrict__ tcb2,
                        float* __restrict__ misc) {
    __shared__ float temb[16], h[16];
    int tid = threadIdx.x;
    float t = tau[0];
    if (tid < 8) {
        float fr = expf(-logf(10000.0f) * (float)tid / 8.0f);
        float a = t * fr;
        temb[tid] = sinf(a);
        temb[tid + 8] = cosf(a);
    }
    __syncthreads();
    if (tid < 16) {
        float acc = tcb1[tid];
#pragma unroll
        for (int i = 0; i < 16; i++) acc += temb[i] * tcW1[i * 16 + tid];
        h[tid] = fmaxf(acc, 0.f);
        misc[tid] = temb[tid];
    }
    __syncthreads();
    if (tid < 32) {
        float acc = tcb2[tid];
#pragma unroll
        for (int i = 0; i < 16; i++) acc += h[i] * tcW2[i * 32 + tid];
        misc[16 + tid] = acc;   // misc[16..31]=scale, misc[32..47]=shift
    }
}

// ---- Phase B: membrane encoder + decoder + knode/vnode precompute ----
__global__ void k_memb(const float* __restrict__ y,
                       const float* __restrict__ W1, const float* __restrict__ b1,
                       const float* __restrict__ W2, const float* __restrict__ b2,
                       const float* __restrict__ decW, const float* __restrict__ decb,
                       const float* __restrict__ Wk, const float* __restrict__ Wv,
                       const float* __restrict__ misc,
                       float* __restrict__ knode, float* __restrict__ vnode,
                       float* __restrict__ outm) {
    __shared__ float sW1[304], sb1[16], sW2[256], sb2[16], sD[48], sdb[3], st[16];
    __shared__ float sWk[256], sWv[256];
    int tid = threadIdx.x;
    for (int i = tid; i < 304; i += 256) sW1[i] = W1[i];
    for (int i = tid; i < 256; i += 256) { sW2[i] = W2[i]; sWk[i] = Wk[i]; sWv[i] = Wv[i]; }
    if (tid < 16) { sb1[tid] = b1[tid]; sb2[tid] = b2[tid]; st[tid] = misc[tid]; }
    if (tid < 48) sD[tid] = decW[tid];
    if (tid < 3) sdb[tid] = decb[tid];
    __syncthreads();
    int n = blockIdx.x * 256 + tid;
    if (n >= NM) return;
    float i0 = y[n * 3], i1 = y[n * 3 + 1], i2 = y[n * 3 + 2];
    float h1[16];
#pragma unroll
    for (int c = 0; c < 16; c++) {
        float acc = sb1[c] + i0 * sW1[c] + i1 * sW1[16 + c] + i2 * sW1[32 + c];
#pragma unroll
        for (int i = 0; i < 16; i++) acc += st[i] * sW1[(3 + i) * 16 + c];
        h1[c] = fmaxf(acc, 0.f);
    }
    float xm[16];
#pragma unroll
    for (int c = 0; c < 16; c++) {
        float acc = sb2[c];
#pragma unroll
        for (int i = 0; i < 16; i++) acc += h1[i] * sW2[i * 16 + c];
        xm[c] = fmaxf(acc, 0.f);
    }
    float kn[16], vn[16];
#pragma unroll
    for (int c = 0; c < 16; c++) {
        float ak = 0.f, av = 0.f;
#pragma unroll
        for (int i = 0; i < 16; i++) { ak += xm[i] * sWk[i * 16 + c]; av += xm[i] * sWv[i * 16 + c]; }
        kn[c] = ak; vn[c] = av;
    }
#pragma unroll
    for (int q = 0; q < 4; q++) {
        reinterpret_cast<float4*>(knode)[n * 4 + q] =
            make_float4(kn[4 * q], kn[4 * q + 1], kn[4 * q + 2], kn[4 * q + 3]);
        reinterpret_cast<float4*>(vnode)[n * 4 + q] =
            make_float4(vn[4 * q], vn[4 * q + 1], vn[4 * q + 2], vn[4 * q + 3]);
    }
#pragma unroll
    for (int k = 0; k < 3; k++) {
        float acc = sdb[k];
#pragma unroll
        for (int i = 0; i < 16; i++) acc += xm[i] * sD[i * 3 + k];
        outm[n * 3 + k] = acc;
    }
}

// ---- Phase C: flow encoder ----
__global__ void k_flow0(const float* __restrict__ x,
                        const float* __restrict__ W, const float* __restrict__ b,
                        const float* __restrict__ misc,
                        float* __restrict__ xf0) {
    __shared__ float sW[304], sb[16], st[16];
    int tid = threadIdx.x;
    for (int i = tid; i < 304; i += 256) sW[i] = W[i];
    if (tid < 16) { sb[tid] = b[tid]; st[tid] = misc[tid]; }
    __syncthreads();
    int n = blockIdx.x * 256 + tid;
    if (n >= NF) return;
    float i0 = x[n * 3], i1 = x[n * 3 + 1], i2 = x[n * 3 + 2];
    float f[16];
#pragma unroll
    for (int c = 0; c < 16; c++) {
        float acc = sb[c] + i0 * sW[c] + i1 * sW[16 + c] + i2 * sW[32 + c];
#pragma unroll
        for (int i = 0; i < 16; i++) acc += st[i] * sW[(3 + i) * 16 + c];
        f[c] = acc;
    }
#pragma unroll
    for (int q = 0; q < 4; q++)
        reinterpret_cast<float4*>(xf0)[n * 4 + q] =
            make_float4(f[4 * q], f[4 * q + 1], f[4 * q + 2], f[4 * q + 3]);
}

// ---- CSR build: histogram ----
__global__ void k_hist(const int* __restrict__ dst_ff, const int* __restrict__ dst_mf,
                       int* __restrict__ cnt, int* __restrict__ cnt2) {
    int gid = blockIdx.x * 256 + threadIdx.x;
    if (gid < EFF) {
        atomicAdd(&cnt[dst_ff[gid]], 1);
    } else if (gid < EFF + EMF) {
        atomicAdd(&cnt2[dst_mf[gid - EFF]], 1);
    }
}

// ---- CSR build: per-block sums (196 blocks x 256) ----
__global__ void k_scanA(const int* __restrict__ cnt, int* __restrict__ bsum, int pad8) {
    __shared__ int red[256];
    int t = threadIdx.x, n = blockIdx.x * 256 + t;
    int c = (n < NF) ? cnt[n] : 0;
    red[t] = pad8 ? ((c + 7) >> 3) : c;
    __syncthreads();
    for (int s = 128; s > 0; s >>= 1) { if (t < s) red[t] += red[t + s]; __syncthreads(); }
    if (t == 0) bsum[blockIdx.x] = red[0];
}

// ---- CSR build: offsets (+ optional batch->dst map, total count) ----
__global__ void k_scanC(const int* __restrict__ cnt, const int* __restrict__ bsum,
                        int* __restrict__ base, int* __restrict__ dstArr,
                        int* __restrict__ nbout, int pad8, int mul) {
    __shared__ int s0[256], s1[256];
    int t = threadIdx.x, b = blockIdx.x, n = b * 256 + t;
    s0[t] = (t < b) ? bsum[t] : 0;
    __syncthreads();
    for (int s = 128; s > 0; s >>= 1) { if (t < s) s0[t] += s0[t + s]; __syncthreads(); }
    int off0 = s0[0];
    __syncthreads();
    int c = (n < NF) ? cnt[n] : 0;
    int bn = pad8 ? ((c + 7) >> 3) : c;
    s0[t] = bn;
    __syncthreads();
    int* cur = s0; int* nxt = s1;
    for (int s = 1; s < 256; s <<= 1) {
        nxt[t] = cur[t] + ((t >= s) ? cur[t - s] : 0);
        __syncthreads();
        int* tmp = cur; cur = nxt; nxt = tmp;
    }
    int excl = cur[t] - bn;
    int off = off0 + excl;
    if (n < NF) base[n] = off * mul;
    if (dstArr) for (int k = 0; k < bn; k++) dstArr[off + k] = n;
    if (nbout && n == NF - 1) nbout[0] = off + bn;
}

// ---- CSR build: scatter edge ids (base arrays become cursors) ----
__global__ void k_scatter(const int* __restrict__ dst_ff, const int* __restrict__ dst_mf,
                          int* __restrict__ baseff, int* __restrict__ basemf,
                          int* __restrict__ eidxp, int* __restrict__ eidx2) {
    int gid = blockIdx.x * 256 + threadIdx.x;
    if (gid < EFF) {
        int d = dst_ff[gid];
        int pos = atomicAdd(&baseff[d], 1);
        eidxp[pos] = gid;
    } else if (gid < EFF + EMF) {
        int e = gid - EFF;
        int d = dst_mf[e];
        int pos = atomicAdd(&basemf[d], 1);
        eidx2[pos] = e;
    }
}

// ---- Phase E: fused NNConv edge kernel, MFMA over dst-sorted 8-edge batches ----
// Each wave processes 16 slots = two 8-edge batches (each batch single-dst).
// After the per-edge MFMA chain, in-wave shfl reduction sums the 8 msgs per
// batch; 16 dword-atomics per BATCH (not per edge) commit to agg.
__global__ void __launch_bounds__(256, 2) k_edge_mfma(
        const float* __restrict__ ea, const int* __restrict__ src,
        const float* __restrict__ K0, const float* __restrict__ kb0,
        const float* __restrict__ K1, const float* __restrict__ kb1,
        const float* __restrict__ K2, const float* __restrict__ kb2,
        const float* __restrict__ xf0, float* __restrict__ agg,
        const int* __restrict__ eidxp, const int* __restrict__ dstArr,
        const int* __restrict__ nb8p) {
    __shared__ __align__(16) char smem_big[32768];   // sK1 fp32 (16KB) then fragK2 bf16 (32KB)
    __shared__ __align__(16) float sK0[384];
    __shared__ __align__(16) float skb0[64];
    __shared__ __align__(16) float sb2[256];
    __shared__ __align__(16) short kh1buf[4][1024];  // per-wave [16 e][64 c] bf16, swizzled
    __shared__ __align__(16) float msgbuf[4][256];   // per-wave [16 e][16 i]

    const int tid = threadIdx.x;
    const int w = tid >> 6, lane = tid & 63;
    const int cl = lane & 15, g = lane >> 4;

    float* sK1 = (float*)smem_big;
    short* fragK2 = (short*)smem_big;
    for (int i = tid; i < 4096; i += 256) sK1[i] = K1[i];
    for (int i = tid; i < 384; i += 256) sK0[i] = K0[i];
    if (tid < 64) skb0[tid] = kb0[tid];
    if (tid < 256) sb2[tid] = kb2[tid];
    __syncthreads();
    // K1 B-frags -> registers (lane holds K1[32s+8g+jj][16n+cl])
    s8 K1B[2][4];
#pragma unroll
    for (int s = 0; s < 2; s++)
#pragma unroll
        for (int n = 0; n < 4; n++) {
            s8 v;
#pragma unroll
            for (int jj = 0; jj < 8; jj++)
                v[jj] = f2b(sK1[(32 * s + 8 * g + jj) * 64 + 16 * n + cl]);
            K1B[s][n] = v;
        }
    float b1v[4];
#pragma unroll
    for (int n = 0; n < 4; n++) b1v[n] = kb1[16 * n + cl];
    __syncthreads();
    // fragK2: A-frag layout of K2^T tiles
    for (int idx = tid; idx < 16384; idx += 256) {
        int n = idx >> 10, s = (idx >> 9) & 1, l2 = (idx >> 3) & 63, jj = idx & 7;
        fragK2[idx] = f2b(K2[(32 * s + 8 * (l2 >> 4) + jj) * 256 + 16 * n + (l2 & 15)]);
    }
    __syncthreads();

    const f4* K04 = (const f4*)sK0;
    const f4* KB04 = (const f4*)skb0;
    short* kh1w = kh1buf[w];
    float* msgw = msgbuf[w];
    const s8* K2f = (const s8*)fragK2;

    const int nb8 = nb8p[0];
    const int NG = (nb8 + 1) >> 1;            // 16-slot groups

    for (int gb = blockIdx.x * 4 + w; gb < NG; gb += gridDim.x * 4) {
        const int eid = eidxp[gb * 16 + cl];  // -1 = sentinel
        f4 xq = {0.f, 0.f, 0.f, 0.f};
        float e0 = 0.f, e1 = 0.f, e2v = 0.f, e3 = 0.f, e4 = 0.f, e5 = 0.f;
        if (eid >= 0) {
            const int si = src[eid];
            xq = *(const f4*)(xf0 + (size_t)si * 16 + g * 4);
            const float2* ep2 = reinterpret_cast<const float2*>(ea + (size_t)eid * 6);
            const float2 p01 = ep2[0], p23 = ep2[1], p45 = ep2[2];
            e0 = p01.x; e1 = p01.y; e2v = p23.x; e3 = p23.y; e4 = p45.x; e5 = p45.y;
        }

        // ---- stage 1: kh0 = relu(ea @ K0 + kb0), built as A-frags ----
        s8 a1[2];
#pragma unroll
        for (int s = 0; s < 2; s++) {
            f4 accA = KB04[8 * s + 2 * g];
            f4 accB = KB04[8 * s + 2 * g + 1];
#pragma unroll
            for (int f = 0; f < 6; f++) {
                const float ef = (f == 0) ? e0 : (f == 1) ? e1 : (f == 2) ? e2v
                               : (f == 3) ? e3 : (f == 4) ? e4 : e5;
                accA += ef * K04[f * 16 + 8 * s + 2 * g];
                accB += ef * K04[f * 16 + 8 * s + 2 * g + 1];
            }
            s8 v;
#pragma unroll
            for (int jj = 0; jj < 4; jj++) v[jj] = f2b(fmaxf(accA[jj], 0.f));
#pragma unroll
            for (int jj = 0; jj < 4; jj++) v[4 + jj] = f2b(fmaxf(accB[jj], 0.f));
            a1[s] = v;
        }

        // ---- stage 2: kh1 = relu(kh0 @ K1 + b1) -> swizzled LDS ----
#pragma unroll
        for (int n = 0; n < 4; n++) {
            f4 c2 = {0.f, 0.f, 0.f, 0.f};
            c2 = __builtin_amdgcn_mfma_f32_16x16x32_bf16(a1[0], K1B[0][n], c2, 0, 0, 0);
            c2 = __builtin_amdgcn_mfma_f32_16x16x32_bf16(a1[1], K1B[1][n], c2, 0, 0, 0);
#pragma unroll
            for (int r = 0; r < 4; r++) {
                const int e = 4 * g + r;
                const int byteoff = (e * 128 + (16 * n + cl) * 2) ^ ((e & 7) << 4);
                *(short*)((char*)kh1w + byteoff) = f2b(fmaxf(c2[r] + b1v[n], 0.f));
            }
        }

        // ---- stage 3: ker tiles (transposed) + lane-local x contraction ----
        s8 a3[2];
#pragma unroll
        for (int s = 0; s < 2; s++) {
            const int byteoff = (cl * 128 + 64 * s + 16 * g) ^ ((cl & 7) << 4);
            a3[s] = *(const s8*)((const char*)kh1w + byteoff);
        }
        float p[16];
#pragma unroll
        for (int n = 0; n < 16; n++) {
            f4 acc = *(const f4*)(sb2 + 16 * n + 4 * g);   // b2 bias init
            acc = __builtin_amdgcn_mfma_f32_16x16x32_bf16(K2f[(2 * n + 0) * 64 + lane], a3[0], acc, 0, 0, 0);
            acc = __builtin_amdgcn_mfma_f32_16x16x32_bf16(K2f[(2 * n + 1) * 64 + lane], a3[1], acc, 0, 0, 0);
            float pv = acc[0] * xq[0] + acc[1] * xq[1] + acc[2] * xq[2] + acc[3] * xq[3];
            pv += __shfl_xor(pv, 16);
            pv += __shfl_xor(pv, 32);
            p[n] = pv;   // sentinel edges: xq==0 in all 4 g-lanes -> pv == 0
        }
        // transpose: lane -> (edge = lane>>2, comp group q = lane&3)
        f4 mv;
        if (g == 0)      mv = (f4){p[0], p[1], p[2], p[3]};
        else if (g == 1) mv = (f4){p[4], p[5], p[6], p[7]};
        else if (g == 2) mv = (f4){p[8], p[9], p[10], p[11]};
        else             mv = (f4){p[12], p[13], p[14], p[15]};
        *(f4*)(msgw + cl * 16 + g * 4) = mv;
        f4 m4 = *(const f4*)(msgw + lane * 4);
        // reduce over the 8 edges of each half-wave batch
#pragma unroll
        for (int s = 4; s <= 16; s <<= 1) {
            m4[0] += __shfl_xor(m4[0], s);
            m4[1] += __shfl_xor(m4[1], s);
            m4[2] += __shfl_xor(m4[2], s);
            m4[3] += __shfl_xor(m4[3], s);
        }
        const int bidx = 2 * gb + (lane >> 5);
        if (bidx < nb8 && (lane & 31) < 4) {
            const int d = dstArr[bidx];
            float* ap = agg + (size_t)d * 16 + (lane & 3) * 4;
            atomicAdd(ap + 0, m4[0]);
            atomicAdd(ap + 1, m4[1]);
            atomicAdd(ap + 2, m4[2]);
            atomicAdd(ap + 3, m4[3]);
        }
    }
}

// ---- Phase F: root + agg/deg + in-register online-softmax attention
//      + FiLM + flow decoder, one thread per flow node ----
__global__ void k_final(const float* __restrict__ xf0, const float* __restrict__ agg,
                        const int* __restrict__ cnt, const int* __restrict__ cnt2,
                        const int* __restrict__ base2c, const int* __restrict__ eidx2,
                        const int* __restrict__ src_mf, const float* __restrict__ ea,
                        const float* __restrict__ knode, const float* __restrict__ vnode,
                        const float* __restrict__ misc,
                        const float* __restrict__ Wq, const float* __restrict__ We,
                        const float* __restrict__ Wr, const float* __restrict__ br,
                        const float* __restrict__ dW, const float* __restrict__ db,
                        float* __restrict__ out) {
    __shared__ float sWr[256], sWq[256], sWe[96], sbr[16], ssc[16], ssh[16], sD[48], sdb[3];
    int tid = threadIdx.x;
    for (int i = tid; i < 256; i += 256) { sWr[i] = Wr[i]; sWq[i] = Wq[i]; }
    if (tid < 96) sWe[tid] = We[tid];
    if (tid < 16) { sbr[tid] = br[tid]; ssc[tid] = misc[16 + tid]; ssh[tid] = misc[32 + tid]; }
    if (tid < 48) sD[tid] = dW[tid];
    if (tid < 3) sdb[tid] = db[tid];
    __syncthreads();
    int n = blockIdx.x * 256 + tid;
    if (n >= NF) return;
    float f[16];
#pragma unroll
    for (int q = 0; q < 4; q++) {
        float4 v = reinterpret_cast<const float4*>(xf0)[n * 4 + q];
        f[4 * q] = v.x; f[4 * q + 1] = v.y; f[4 * q + 2] = v.z; f[4 * q + 3] = v.w;
    }
    float r[16], qv[16];
#pragma unroll
    for (int c = 0; c < 16; c++) {
        float ar = sbr[c], aq = 0.f;
#pragma unroll
        for (int i = 0; i < 16; i++) { ar += f[i] * sWr[i * 16 + c]; aq += f[i] * sWq[i * 16 + c]; }
        r[c] = ar; qv[c] = aq;
    }
    // online-softmax cross attention over this node's mf segment
    float num[16];
#pragma unroll
    for (int i = 0; i < 16; i++) num[i] = 0.f;
    float den = 0.f, m = -3.0e38f;
    int c2 = cnt2[n];
    int st = base2c[n] - c2;    // cursor end - count = segment start
    for (int j = 0; j < c2; j++) {
        int eid = eidx2[st + j];
        int s = src_mf[eid];
        const float2* ep = reinterpret_cast<const float2*>(ea + (size_t)eid * 6);
        float2 e01 = ep[0], e23 = ep[1], e45 = ep[2];
        float sc = 0.f;
#pragma unroll
        for (int q4i = 0; q4i < 4; q4i++) {
            float4 k4 = reinterpret_cast<const float4*>(knode)[(size_t)s * 4 + q4i];
            float kk[4] = {k4.x, k4.y, k4.z, k4.w};
#pragma unroll
            for (int jj = 0; jj < 4; jj++) {
                int c = 4 * q4i + jj;
                kk[jj] += e01.x * sWe[c] + e01.y * sWe[16 + c] + e23.x * sWe[32 + c]
                        + e23.y * sWe[48 + c] + e45.x * sWe[64 + c] + e45.y * sWe[80 + c];
                sc += qv[c] * kk[jj];
            }
        }
        sc *= 0.25f;
        if (sc > m) {
            float rs = expf(m - sc);   // m=-3e38 first time -> rs=0, den/num are 0
            den *= rs;
#pragma unroll
            for (int i = 0; i < 16; i++) num[i] *= rs;
            m = sc;
        }
        float e = expf(sc - m);
        den += e;
#pragma unroll
        for (int q4i = 0; q4i < 4; q4i++) {
            float4 v4 = reinterpret_cast<const float4*>(vnode)[(size_t)s * 4 + q4i];
            num[4 * q4i + 0] += e * v4.x;
            num[4 * q4i + 1] += e * v4.y;
            num[4 * q4i + 2] += e * v4.z;
            num[4 * q4i + 3] += e * v4.w;
        }
    }
    float rdn = 1.0f / (den + 1e-16f);
    float rdg = 1.0f / fmaxf((float)cnt[n], 1.0f);
    float xo[16];
#pragma unroll
    for (int q = 0; q < 4; q++) {
        float4 a4 = reinterpret_cast<const float4*>(agg)[n * 4 + q];
        float av[4] = {a4.x, a4.y, a4.z, a4.w};
#pragma unroll
        for (int jj = 0; jj < 4; jj++) {
            int c = 4 * q + jj;
            float v = r[c] + av[jj] * rdg + num[c] * rdn;
            float rr = fmaxf(v, 0.f);
            xo[c] = rr + (rr * ssc[c] + ssh[c]);
        }
    }
#pragma unroll
    for (int k = 0; k < 3; k++) {
        float acc = sdb[k];
#pragma unroll
        for (int i = 0; i < 16; i++) acc += xo[i] * sD[i * 3 + k];
        out[n * 3 + k] = acc;
    }
}

extern "C" void kernel_launch(void* const* d_in, const int* in_sizes, int n_in,
                              void* d_out, int out_size, void* d_ws, size_t ws_size,
                              hipStream_t stream) {
    const float* flow_x   = (const float*)d_in[0];
    const float* memb_y   = (const float*)d_in[1];
    const float* tau      = (const float*)d_in[2];
    const float* ea_ff    = (const float*)d_in[3];
    const float* ea_mf    = (const float*)d_in[4];
    const float* enc_f_W  = (const float*)d_in[5];
    const float* enc_f_b  = (const float*)d_in[6];
    const float* enc_m_W1 = (const float*)d_in[7];
    const float* enc_m_b1 = (const float*)d_in[8];
    const float* enc_m_W2 = (const float*)d_in[9];
    const float* enc_m_b2 = (const float*)d_in[10];
    const float* K0       = (const float*)d_in[11];
    const float* kb0      = (const float*)d_in[12];
    const float* K1       = (const float*)d_in[13];
    const float* kb1      = (const float*)d_in[14];
    const float* K2       = (const float*)d_in[15];
    const float* kb2      = (const float*)d_in[16];
    const float* W_root   = (const float*)d_in[17];
    const float* b_root   = (const float*)d_in[18];
    const float* Wq       = (const float*)d_in[19];
    const float* Wk       = (const float*)d_in[20];
    const float* We       = (const float*)d_in[21];
    const float* Wv       = (const float*)d_in[22];
    const float* tc_W1    = (const float*)d_in[23];
    const float* tc_b1    = (const float*)d_in[24];
    const float* tc_W2    = (const float*)d_in[25];
    const float* tc_b2    = (const float*)d_in[26];
    const float* dec_f_W  = (const float*)d_in[27];
    const float* dec_f_b  = (const float*)d_in[28];
    const float* dec_m_W  = (const float*)d_in[29];
    const float* dec_m_b  = (const float*)d_in[30];
    const int* src_ff = (const int*)d_in[31];
    const int* dst_ff = (const int*)d_in[32];
    const int* src_mf = (const int*)d_in[33];
    const int* dst_mf = (const int*)d_in[34];

    float* out = (float*)d_out;
    float* ws = (float*)d_ws;

    // layout (floats/ints); total 13.85 MB < 14.52 MB proven-safe
    float* misc  = ws;                          // 64
    float* knode = ws + 64;                     // NM*16
    float* vnode = knode + (size_t)NM * 16;     // NM*16
    float* xf0   = vnode + (size_t)NM * 16;     // NF*16
    float* agg   = xf0 + (size_t)NF * 16;       // NF*16   (zeroed)
    int* cnt   = (int*)(agg + (size_t)NF * 16); // NF      (zeroed)
    int* cnt2  = cnt + NF;                      // NF      (zeroed)
    int* base  = cnt2 + NF;                     // NF
    int* base2 = base + NF;                     // NF
    int* dstArr = base2 + NF;                   // 150000
    int* eidxp  = dstArr + 150000;              // 1,152,000 (0xFF-init)
    int* eidx2  = eidxp + 1152000;              // EMF
    int* bsA    = eidx2 + EMF;                  // 256
    int* bsB    = bsA + 256;                    // 256
    int* nb8p   = bsB + 256;                    // 16

    hipMemsetAsync(agg, 0, ((size_t)NF * 16 + 2 * NF) * sizeof(float), stream);
    hipMemsetAsync(eidxp, 0xFF, 1152000 * sizeof(int), stream);

    k_small<<<1, 64, 0, stream>>>(tau, tc_W1, tc_b1, tc_W2, tc_b2, misc);
    k_memb<<<(NM + 255) / 256, 256, 0, stream>>>(memb_y, enc_m_W1, enc_m_b1, enc_m_W2,
                                                 enc_m_b2, dec_m_W, dec_m_b, Wk, Wv, misc,
                                                 knode, vnode, out + (size_t)NF * 3);
    k_flow0<<<(NF + 255) / 256, 256, 0, stream>>>(flow_x, enc_f_W, enc_f_b, misc, xf0);
    k_hist<<<(EFF + EMF + 255) / 256, 256, 0, stream>>>(dst_ff, dst_mf, cnt, cnt2);
    k_scanA<<<196, 256, 0, stream>>>(cnt, bsA, 1);
    k_scanA<<<196, 256, 0, stream>>>(cnt2, bsB, 0);
    k_scanC<<<196, 256, 0, stream>>>(cnt, bsA, base, dstArr, nb8p, 1, 8);
    k_scanC<<<196, 256, 0, stream>>>(cnt2, bsB, base2, nullptr, nullptr, 0, 1);
    k_scatter<<<(EFF + EMF + 255) / 256, 256, 0, stream>>>(dst_ff, dst_mf, base, base2,
                                                           eidxp, eidx2);
    k_edge_mfma<<<2048, 256, 0, stream>>>(ea_ff, src_ff, K0, kb0, K1, kb1, K2, kb2,
                                          xf0, agg, eidxp, dstArr, nb8p);
    k_final<<<(NF + 255) / 256, 256, 0, stream>>>(xf0, agg, cnt, cnt2, base2, eidx2,
                                                  src_mf, ea_mf, knode, vnode, misc,
                                                  Wq, We, W_root, b_root,
                                                  dec_f_W, dec_f_b, out);
}